// Round 1
// baseline (513.062 us; speedup 1.0000x reference)
//
#include <hip/hip_runtime.h>
#include <hip/hip_bf16.h>

#define D_MODEL 768
#define D_HIDDEN 2048
#define NHEADS 12
#define BATCH 4
#define SEQ 128
#define MROWS (BATCH*SEQ)                      // 512
#define SCORE_ELEMS (BATCH*NHEADS*SEQ*SEQ)     // 786432
#define REG_OFF SCORE_ELEMS
#define FIRES_OFF (SCORE_ELEMS + 1)

typedef __attribute__((ext_vector_type(8))) short bf16x8;
typedef __attribute__((ext_vector_type(4))) float f32x4;

static __device__ __forceinline__ unsigned short f2bf(float f) {
    union { float f; unsigned u; } v; v.f = f;
    unsigned u = v.u;
    return (unsigned short)((u + 0x7FFFu + ((u >> 16) & 1u)) >> 16);  // RNE
}

// ---------------------------------------------------------------------------
// Kernel 1: encoder GEMM  out = relu(x @ W + b)
// M=512 (b*s), N=2048 (h), K=768. BM=64, BN=128, BK=16. fp32 accum.
// fp64 cleanup for |preact| < 3e-4 so fires signs match the true value.
// ---------------------------------------------------------------------------
__global__ __launch_bounds__(256) void enc_kernel(
    const float* __restrict__ x, const float* __restrict__ W,
    const float* __restrict__ bias, float* __restrict__ outbuf)
{
    __shared__ float xs[64][16];
    __shared__ float wt[16][128];
    const int t  = threadIdx.x;
    const int m0 = blockIdx.y * 64;
    const int n0 = blockIdx.x * 128;
    const int rg = t >> 5;    // 0..7  -> 8 rows each
    const int cg = t & 31;    // 0..31 -> 4 cols each

    float acc[8][4];
    #pragma unroll
    for (int i = 0; i < 8; ++i)
        #pragma unroll
        for (int c = 0; c < 4; ++c) acc[i][c] = 0.f;

    for (int kk = 0; kk < D_MODEL; kk += 16) {
        #pragma unroll
        for (int u = 0; u < 4; ++u) {
            int idx = t + 256 * u; int r = idx >> 4, j = idx & 15;
            xs[r][j] = x[(size_t)(m0 + r) * D_MODEL + kk + j];
        }
        #pragma unroll
        for (int u = 0; u < 8; ++u) {
            int idx = t + 256 * u; int r = idx >> 7, c = idx & 127;
            wt[r][c] = W[(size_t)(kk + r) * D_HIDDEN + n0 + c];
        }
        __syncthreads();
        #pragma unroll
        for (int j = 0; j < 16; ++j) {
            float a[8];
            #pragma unroll
            for (int i = 0; i < 8; ++i) a[i] = xs[rg * 8 + i][j];
            const float4 wv = *reinterpret_cast<const float4*>(&wt[j][cg * 4]);
            const float wr[4] = {wv.x, wv.y, wv.z, wv.w};
            #pragma unroll
            for (int i = 0; i < 8; ++i)
                #pragma unroll
                for (int c = 0; c < 4; ++c) acc[i][c] = fmaf(a[i], wr[c], acc[i][c]);
        }
        __syncthreads();
    }

    #pragma unroll
    for (int i = 0; i < 8; ++i) {
        const int m = m0 + rg * 8 + i;
        #pragma unroll
        for (int c = 0; c < 4; ++c) {
            const int h = n0 + cg * 4 + c;
            float pre = acc[i][c] + bias[h];
            if (fabsf(pre) < 3e-4f) {
                // near-zero: recompute this dot in fp64 (rare, ~hundreds total)
                const float* xr = x + (size_t)m * D_MODEL;
                const float* wc = W + h;
                double s = (double)bias[h];
                for (int dd = 0; dd < D_MODEL; ++dd)
                    s += (double)xr[dd] * (double)wc[(size_t)dd * D_HIDDEN];
                pre = (float)s;
            }
            outbuf[(size_t)m * D_HIDDEN + h] = fmaxf(pre, 0.f);
        }
    }
}

// ---------------------------------------------------------------------------
// Kernel 2: fires + reg_loss streaming pass (store-BW bound, ~512 MiB writes)
// grid = 4b * 128q * 4kc blocks; block handles (b,q, 32 k-rows), 2048 h.
// ---------------------------------------------------------------------------
__global__ __launch_bounds__(256) void fires_kernel(
    const float* __restrict__ qbuf, const float* __restrict__ kbuf,
    float* __restrict__ out)
{
    const int t  = threadIdx.x;
    const int bi = blockIdx.x;
    const int kc = bi & 3;
    const int q  = (bi >> 2) & (SEQ - 1);
    const int b  = bi >> 9;

    const float* qrow = qbuf + (size_t)(b * SEQ + q) * D_HIDDEN;
    float qv[8];
    #pragma unroll
    for (int j = 0; j < 8; ++j) qv[j] = qrow[t + 256 * j];

    float racc = 0.f;
    const size_t fb = (size_t)FIRES_OFF +
                      ((size_t)(b * SEQ + q) * SEQ + (size_t)kc * 32) * D_HIDDEN + t;
    const float* kbase = kbuf + (size_t)(b * SEQ + kc * 32) * D_HIDDEN;

    for (int k0 = 0; k0 < 32; ++k0) {
        const float* kr = kbase + (size_t)k0 * D_HIDDEN;
        float* op = out + fb + (size_t)k0 * D_HIDDEN;
        #pragma unroll
        for (int j = 0; j < 8; ++j) {
            const float kv = kr[t + 256 * j];
            const float p  = qv[j] * kv;
            op[256 * j] = (p > 0.f) ? 1.0f : 0.0f;
            racc += sqrtf(p + 1e-6f);
        }
    }

    // wave reduce then cross-wave via LDS, one atomic per block
    #pragma unroll
    for (int off = 32; off > 0; off >>= 1) racc += __shfl_down(racc, off);
    __shared__ float rs[4];
    if ((t & 63) == 0) rs[t >> 6] = racc;
    __syncthreads();
    if (t == 0) atomicAdd(out + REG_OFF, (rs[0] + rs[1] + rs[2] + rs[3]) * 1e-3f);
}

// ---------------------------------------------------------------------------
// Kernel 3: score via bf16 MFMA. For each (b,n): C[q,k] = (q .* Wdec[:,n]) @ K^T
// grid = 4b * 12n * (2x2 tiles of 64x64); block = 4 waves, wave = 32x32.
// ---------------------------------------------------------------------------
__global__ __launch_bounds__(256) void score_kernel(
    const float* __restrict__ qbuf, const float* __restrict__ kbuf,
    const float* __restrict__ Wdec, const float* __restrict__ bdec,
    float* __restrict__ out)
{
    __shared__ float wcol[D_HIDDEN];
    const int t   = threadIdx.x;
    const int bi  = blockIdx.x;
    const int sub = bi & 3;
    const int pr  = bi >> 2;
    const int n   = pr % NHEADS;
    const int b   = pr / NHEADS;

    for (int idx = t; idx < D_HIDDEN; idx += 256)
        wcol[idx] = Wdec[(size_t)idx * NHEADS + n];
    __syncthreads();

    const int q0   = (sub >> 1) * 64;
    const int k0   = (sub & 1) * 64;
    const int w    = t >> 6;
    const int lane = t & 63;
    const int lrow = lane & 15;
    const int koff = (lane >> 4) * 8;
    const int qw   = q0 + (w >> 1) * 32;
    const int kw   = k0 + (w & 1) * 32;

    f32x4 acc[2][2];
    #pragma unroll
    for (int i = 0; i < 2; ++i)
        #pragma unroll
        for (int j = 0; j < 2; ++j) { f32x4 z = {0.f, 0.f, 0.f, 0.f}; acc[i][j] = z; }

    const float* qb = qbuf + (size_t)b * SEQ * D_HIDDEN;
    const float* kb = kbuf + (size_t)b * SEQ * D_HIDDEN;

    for (int kk = 0; kk < D_HIDDEN; kk += 32) {
        const int h0 = kk + koff;
        float wv[8];
        #pragma unroll
        for (int i = 0; i < 8; ++i) wv[i] = wcol[h0 + i];

        bf16x8 afrag[2], bfrag[2];
        #pragma unroll
        for (int fi = 0; fi < 2; ++fi) {
            const float* qp = qb + (size_t)(qw + fi * 16 + lrow) * D_HIDDEN + h0;
            const float4 q1 = *reinterpret_cast<const float4*>(qp);
            const float4 q2 = *reinterpret_cast<const float4*>(qp + 4);
            const float qf[8] = {q1.x, q1.y, q1.z, q1.w, q2.x, q2.y, q2.z, q2.w};
            #pragma unroll
            for (int i = 0; i < 8; ++i) afrag[fi][i] = (short)f2bf(qf[i] * wv[i]);
        }
        #pragma unroll
        for (int fj = 0; fj < 2; ++fj) {
            const float* kp = kb + (size_t)(kw + fj * 16 + lrow) * D_HIDDEN + h0;
            const float4 k1 = *reinterpret_cast<const float4*>(kp);
            const float4 k2 = *reinterpret_cast<const float4*>(kp + 4);
            const float kf[8] = {k1.x, k1.y, k1.z, k1.w, k2.x, k2.y, k2.z, k2.w};
            #pragma unroll
            for (int i = 0; i < 8; ++i) bfrag[fj][i] = (short)f2bf(kf[i]);
        }
        #pragma unroll
        for (int fi = 0; fi < 2; ++fi)
            #pragma unroll
            for (int fj = 0; fj < 2; ++fj)
                acc[fi][fj] = __builtin_amdgcn_mfma_f32_16x16x32_bf16(
                    afrag[fi], bfrag[fj], acc[fi][fj], 0, 0, 0);
    }

    const float bd   = bdec[n];
    const int   outb = (b * NHEADS + n) * SEQ * SEQ;
    #pragma unroll
    for (int fi = 0; fi < 2; ++fi)
        #pragma unroll
        for (int fj = 0; fj < 2; ++fj)
            #pragma unroll
            for (int j = 0; j < 4; ++j) {
                const int row = qw + fi * 16 + (lane >> 4) * 4 + j;
                const int col = kw + fj * 16 + (lane & 15);
                out[outb + row * SEQ + col] = acc[fi][fj][j] * 0.125f + bd;
            }
}

// ---------------------------------------------------------------------------
extern "C" void kernel_launch(void* const* d_in, const int* in_sizes, int n_in,
                              void* d_out, int out_size, void* d_ws, size_t ws_size,
                              hipStream_t stream) {
    const float* x  = (const float*)d_in[0];
    const float* WQ = (const float*)d_in[1];
    const float* WK = (const float*)d_in[2];
    const float* bQ = (const float*)d_in[3];
    const float* bK = (const float*)d_in[4];
    const float* Wd = (const float*)d_in[5];
    const float* bd = (const float*)d_in[6];
    float* out  = (float*)d_out;
    float* qbuf = (float*)d_ws;                                // 4 MB
    float* kbuf = qbuf + (size_t)MROWS * D_HIDDEN;             // 4 MB

    dim3 b256(256);
    dim3 g1(D_HIDDEN / 128, MROWS / 64);                       // 16 x 8
    enc_kernel<<<g1, b256, 0, stream>>>(x, WQ, bQ, qbuf);
    enc_kernel<<<g1, b256, 0, stream>>>(x, WK, bK, kbuf);

    // zero the reg_loss accumulator slot (harness doesn't re-poison between replays)
    hipMemsetAsync((char*)d_out + (size_t)REG_OFF * sizeof(float), 0, sizeof(float), stream);

    score_kernel<<<dim3(BATCH * NHEADS * 4), b256, 0, stream>>>(qbuf, kbuf, Wd, bd, out);
    fires_kernel<<<dim3(BATCH * SEQ * 4), b256, 0, stream>>>(qbuf, kbuf, out);
}

// Round 3
// 393.471 us; speedup vs baseline: 1.3039x; 1.3039x over previous
//
#include <hip/hip_runtime.h>
#include <hip/hip_bf16.h>

#define D_MODEL 768
#define D_HIDDEN 2048
#define NHEADS 12
#define BATCH 4
#define SEQ 128
#define MROWS (BATCH*SEQ)                      // 512
#define SCORE_ELEMS (BATCH*NHEADS*SEQ*SEQ)     // 786432
#define REG_OFF SCORE_ELEMS
#define FIRES_OFF (SCORE_ELEMS + 1)
#define TRIGMAX 8192

typedef __attribute__((ext_vector_type(8))) short bf16x8;
typedef __attribute__((ext_vector_type(4))) float f32x4;

static __device__ __forceinline__ unsigned short f2bf(float f) {
    union { float f; unsigned u; } v; v.f = f;
    unsigned u = v.u;
    return (unsigned short)((u + 0x7FFFu + ((u >> 16) & 1u)) >> 16);  // RNE
}

// ---------------------------------------------------------------------------
// Kernel 1: encoder GEMM  out = relu(x @ W + b)
// M=512, N=2048, K=768. BM=64, BN=128, BK=16, fp32 accum.
// Near-zero preacts (|pre| < 3e-4) are pushed to a trigger list; a separate
// fix kernel recomputes them in fp64 so fires signs match the true value.
// ---------------------------------------------------------------------------
__global__ __launch_bounds__(256) void enc_kernel(
    const float* __restrict__ x, const float* __restrict__ W,
    const float* __restrict__ bias, float* __restrict__ outbuf,
    unsigned* __restrict__ trigc, unsigned* __restrict__ trig,
    int cap, int bufid)
{
    __shared__ float xs[64][16];
    __shared__ float wt[16][128];
    const int t  = threadIdx.x;
    const int m0 = blockIdx.y * 64;
    const int n0 = blockIdx.x * 128;
    const int rg = t >> 5;
    const int cg = t & 31;

    float acc[8][4];
    #pragma unroll
    for (int i = 0; i < 8; ++i)
        #pragma unroll
        for (int c = 0; c < 4; ++c) acc[i][c] = 0.f;

    for (int kk = 0; kk < D_MODEL; kk += 16) {
        #pragma unroll
        for (int u = 0; u < 4; ++u) {
            int idx = t + 256 * u; int r = idx >> 4, j = idx & 15;
            xs[r][j] = x[(size_t)(m0 + r) * D_MODEL + kk + j];
        }
        #pragma unroll
        for (int u = 0; u < 8; ++u) {
            int idx = t + 256 * u; int r = idx >> 7, c = idx & 127;
            wt[r][c] = W[(size_t)(kk + r) * D_HIDDEN + n0 + c];
        }
        __syncthreads();
        #pragma unroll
        for (int j = 0; j < 16; ++j) {
            float a[8];
            #pragma unroll
            for (int i = 0; i < 8; ++i) a[i] = xs[rg * 8 + i][j];
            const float4 wv = *reinterpret_cast<const float4*>(&wt[j][cg * 4]);
            const float wr[4] = {wv.x, wv.y, wv.z, wv.w};
            #pragma unroll
            for (int i = 0; i < 8; ++i)
                #pragma unroll
                for (int c = 0; c < 4; ++c) acc[i][c] = fmaf(a[i], wr[c], acc[i][c]);
        }
        __syncthreads();
    }

    #pragma unroll
    for (int i = 0; i < 8; ++i) {
        const int m = m0 + rg * 8 + i;
        #pragma unroll
        for (int c = 0; c < 4; ++c) {
            const int h = n0 + cg * 4 + c;
            float pre = acc[i][c] + bias[h];
            if (fabsf(pre) < 3e-4f) {
                if (cap > 0) {
                    unsigned idx = atomicAdd(trigc, 1u);
                    if ((int)idx < cap)
                        trig[idx] = ((unsigned)bufid << 20) | ((unsigned)m << 11) | (unsigned)h;
                } else {
                    // fallback: inline fp64 recompute
                    const float* xr = x + (size_t)m * D_MODEL;
                    const float* wc = W + h;
                    double s = (double)bias[h];
                    for (int dd = 0; dd < D_MODEL; ++dd)
                        s += (double)xr[dd] * (double)wc[(size_t)dd * D_HIDDEN];
                    pre = (float)s;
                }
            }
            outbuf[(size_t)m * D_HIDDEN + h] = fmaxf(pre, 0.f);
        }
    }
}

// ---------------------------------------------------------------------------
// Kernel 1b: fp64 fix for near-zero preacts. One block per trigger (strided).
// ---------------------------------------------------------------------------
__global__ __launch_bounds__(256) void fix_kernel(
    const float* __restrict__ x,
    const float* __restrict__ WQ, const float* __restrict__ WK,
    const float* __restrict__ bQ, const float* __restrict__ bK,
    float* __restrict__ qbuf, float* __restrict__ kbuf,
    const unsigned* __restrict__ trigc, const unsigned* __restrict__ trig,
    int cap)
{
    __shared__ double red[4];
    const unsigned n = min(*trigc, (unsigned)cap);
    for (unsigned i = blockIdx.x; i < n; i += gridDim.x) {
        const unsigned e = trig[i];
        const int h = e & 2047, m = (e >> 11) & 511, bid = (int)(e >> 20);
        const float* W  = bid ? WK : WQ;
        const float* bb = bid ? bK : bQ;
        float* ob       = bid ? kbuf : qbuf;
        const float* xr = x + (size_t)m * D_MODEL;
        double s = 0.0;
        for (int dd = threadIdx.x; dd < D_MODEL; dd += 256)
            s += (double)xr[dd] * (double)W[(size_t)dd * D_HIDDEN + h];
        #pragma unroll
        for (int off = 32; off > 0; off >>= 1) s += __shfl_down(s, off);
        if ((threadIdx.x & 63) == 0) red[threadIdx.x >> 6] = s;
        __syncthreads();
        if (threadIdx.x == 0) {
            double tot = red[0] + red[1] + red[2] + red[3] + (double)bb[h];
            ob[(size_t)m * D_HIDDEN + h] = fmaxf((float)tot, 0.f);
        }
        __syncthreads();
    }
}

// ---------------------------------------------------------------------------
// Kernel 2: fires + reg_loss streaming pass (store-BW bound, ~512 MiB writes)
// Vectorized: fires row r starts at out index 786433 + r*2048 (== 1 mod 4),
// so h in [3, 2046] are 511 aligned float4 NT stores; h in {0,1,2,2047} scalar.
// grid = 4b * 128q * 4kc blocks; block handles (b,q, 32 k-rows).
// ---------------------------------------------------------------------------
__global__ __launch_bounds__(256) void fires_kernel(
    const float* __restrict__ qbuf, const float* __restrict__ kbuf,
    float* __restrict__ out)
{
    const int t  = threadIdx.x;
    const int bi = blockIdx.x;
    const int kc = bi & 3;
    const int q  = (bi >> 2) & (SEQ - 1);
    const int b  = bi >> 9;

    const float* qrow = qbuf + (size_t)(b * SEQ + q) * D_HIDDEN;

    const int h1 = 3 + 4 * t;          // vector 1: h1..h1+3   (h = 3..1026)
    const int h2 = h1 + 1024;          // vector 2: h2..h2+3   (h = 1027..2046), t<255
    const bool has2 = (t < 255);

    float qv1[4], qv2[4];
    #pragma unroll
    for (int e = 0; e < 4; ++e) qv1[e] = qrow[h1 + e];
    #pragma unroll
    for (int e = 0; e < 4; ++e) qv2[e] = has2 ? qrow[h2 + e] : 0.f;
    // edge elements: t=0,1,2 -> h=t ; t=3 -> h=2047
    const int he = (t < 3) ? t : 2047;
    const float qve = (t < 4) ? qrow[he] : 0.f;

    float racc = 0.f;
    const size_t rowbase = (size_t)(b * SEQ + q) * SEQ + (size_t)kc * 32;
    const float* kbase = kbuf + (size_t)(b * SEQ + kc * 32) * D_HIDDEN;

    for (int k0 = 0; k0 < 32; ++k0) {
        const float* kr = kbase + (size_t)k0 * D_HIDDEN;
        float* orow = out + FIRES_OFF + (rowbase + k0) * D_HIDDEN;

        f32x4 f1;
        {
            float p0 = qv1[0] * kr[h1 + 0];
            float p1 = qv1[1] * kr[h1 + 1];
            float p2 = qv1[2] * kr[h1 + 2];
            float p3 = qv1[3] * kr[h1 + 3];
            f1.x = (p0 > 0.f) ? 1.f : 0.f;
            f1.y = (p1 > 0.f) ? 1.f : 0.f;
            f1.z = (p2 > 0.f) ? 1.f : 0.f;
            f1.w = (p3 > 0.f) ? 1.f : 0.f;
            racc += sqrtf(p0 + 1e-6f) + sqrtf(p1 + 1e-6f)
                  + sqrtf(p2 + 1e-6f) + sqrtf(p3 + 1e-6f);
        }
        __builtin_nontemporal_store(f1, (f32x4*)(orow + h1));

        if (has2) {
            f32x4 f2;
            float p0 = qv2[0] * kr[h2 + 0];
            float p1 = qv2[1] * kr[h2 + 1];
            float p2 = qv2[2] * kr[h2 + 2];
            float p3 = qv2[3] * kr[h2 + 3];
            f2.x = (p0 > 0.f) ? 1.f : 0.f;
            f2.y = (p1 > 0.f) ? 1.f : 0.f;
            f2.z = (p2 > 0.f) ? 1.f : 0.f;
            f2.w = (p3 > 0.f) ? 1.f : 0.f;
            racc += sqrtf(p0 + 1e-6f) + sqrtf(p1 + 1e-6f)
                  + sqrtf(p2 + 1e-6f) + sqrtf(p3 + 1e-6f);
            __builtin_nontemporal_store(f2, (f32x4*)(orow + h2));
        }

        if (t < 4) {
            const float pe = qve * kr[he];
            __builtin_nontemporal_store((pe > 0.f) ? 1.f : 0.f, orow + he);
            racc += sqrtf(pe + 1e-6f);
        }
    }

    #pragma unroll
    for (int off = 32; off > 0; off >>= 1) racc += __shfl_down(racc, off);
    __shared__ float rs[4];
    if ((t & 63) == 0) rs[t >> 6] = racc;
    __syncthreads();
    if (t == 0) atomicAdd(out + REG_OFF, (rs[0] + rs[1] + rs[2] + rs[3]) * 1e-3f);
}

// ---------------------------------------------------------------------------
// Kernel 3: score via bf16 MFMA. For each (b,n): C[q,k] = (q .* Wdec[:,n]) @ K^T
// ---------------------------------------------------------------------------
__global__ __launch_bounds__(256) void score_kernel(
    const float* __restrict__ qbuf, const float* __restrict__ kbuf,
    const float* __restrict__ Wdec, const float* __restrict__ bdec,
    float* __restrict__ out)
{
    __shared__ float wcol[D_HIDDEN];
    const int t   = threadIdx.x;
    const int bi  = blockIdx.x;
    const int sub = bi & 3;
    const int pr  = bi >> 2;
    const int n   = pr % NHEADS;
    const int b   = pr / NHEADS;

    for (int idx = t; idx < D_HIDDEN; idx += 256)
        wcol[idx] = Wdec[(size_t)idx * NHEADS + n];
    __syncthreads();

    const int q0   = (sub >> 1) * 64;
    const int k0   = (sub & 1) * 64;
    const int w    = t >> 6;
    const int lane = t & 63;
    const int lrow = lane & 15;
    const int koff = (lane >> 4) * 8;
    const int qw   = q0 + (w >> 1) * 32;
    const int kw   = k0 + (w & 1) * 32;

    f32x4 acc[2][2];
    #pragma unroll
    for (int i = 0; i < 2; ++i)
        #pragma unroll
        for (int j = 0; j < 2; ++j) { f32x4 z = {0.f, 0.f, 0.f, 0.f}; acc[i][j] = z; }

    const float* qb = qbuf + (size_t)b * SEQ * D_HIDDEN;
    const float* kb = kbuf + (size_t)b * SEQ * D_HIDDEN;

    for (int kk = 0; kk < D_HIDDEN; kk += 32) {
        const int h0 = kk + koff;
        float wv[8];
        #pragma unroll
        for (int i = 0; i < 8; ++i) wv[i] = wcol[h0 + i];

        bf16x8 afrag[2], bfrag[2];
        #pragma unroll
        for (int fi = 0; fi < 2; ++fi) {
            const float* qp = qb + (size_t)(qw + fi * 16 + lrow) * D_HIDDEN + h0;
            const float4 q1 = *reinterpret_cast<const float4*>(qp);
            const float4 q2 = *reinterpret_cast<const float4*>(qp + 4);
            const float qf[8] = {q1.x, q1.y, q1.z, q1.w, q2.x, q2.y, q2.z, q2.w};
            #pragma unroll
            for (int i = 0; i < 8; ++i) afrag[fi][i] = (short)f2bf(qf[i] * wv[i]);
        }
        #pragma unroll
        for (int fj = 0; fj < 2; ++fj) {
            const float* kp = kb + (size_t)(kw + fj * 16 + lrow) * D_HIDDEN + h0;
            const float4 k1 = *reinterpret_cast<const float4*>(kp);
            const float4 k2 = *reinterpret_cast<const float4*>(kp + 4);
            const float kf[8] = {k1.x, k1.y, k1.z, k1.w, k2.x, k2.y, k2.z, k2.w};
            #pragma unroll
            for (int i = 0; i < 8; ++i) bfrag[fj][i] = (short)f2bf(kf[i]);
        }
        #pragma unroll
        for (int fi = 0; fi < 2; ++fi)
            #pragma unroll
            for (int fj = 0; fj < 2; ++fj)
                acc[fi][fj] = __builtin_amdgcn_mfma_f32_16x16x32_bf16(
                    afrag[fi], bfrag[fj], acc[fi][fj], 0, 0, 0);
    }

    const float bd   = bdec[n];
    const int   outb = (b * NHEADS + n) * SEQ * SEQ;
    #pragma unroll
    for (int fi = 0; fi < 2; ++fi)
        #pragma unroll
        for (int fj = 0; fj < 2; ++fj)
            #pragma unroll
            for (int j = 0; j < 4; ++j) {
                const int row = qw + fi * 16 + (lane >> 4) * 4 + j;
                const int col = kw + fj * 16 + (lane & 15);
                out[outb + row * SEQ + col] = acc[fi][fj][j] * 0.125f + bd;
            }
}

// ---------------------------------------------------------------------------
extern "C" void kernel_launch(void* const* d_in, const int* in_sizes, int n_in,
                              void* d_out, int out_size, void* d_ws, size_t ws_size,
                              hipStream_t stream) {
    const float* x  = (const float*)d_in[0];
    const float* WQ = (const float*)d_in[1];
    const float* WK = (const float*)d_in[2];
    const float* bQ = (const float*)d_in[3];
    const float* bK = (const float*)d_in[4];
    const float* Wd = (const float*)d_in[5];
    const float* bd = (const float*)d_in[6];
    float* out  = (float*)d_out;
    float* qbuf = (float*)d_ws;                                // 4 MB
    float* kbuf = qbuf + (size_t)MROWS * D_HIDDEN;             // 4 MB
    unsigned* trigc = (unsigned*)(kbuf + (size_t)MROWS * D_HIDDEN);
    unsigned* trig  = trigc + 1;
    const size_t need = (size_t)8 * 1024 * 1024 + 4 + (size_t)TRIGMAX * 4;
    const int cap = (ws_size >= need) ? TRIGMAX : 0;

    dim3 b256(256);
    dim3 g1(D_HIDDEN / 128, MROWS / 64);                       // 16 x 8

    if (cap > 0) (void)hipMemsetAsync(trigc, 0, 4, stream);
    // zero the reg_loss accumulator slot (harness doesn't re-poison between replays)
    (void)hipMemsetAsync((char*)d_out + (size_t)REG_OFF * sizeof(float), 0, sizeof(float), stream);

    enc_kernel<<<g1, b256, 0, stream>>>(x, WQ, bQ, qbuf, trigc, trig, cap, 0);
    enc_kernel<<<g1, b256, 0, stream>>>(x, WK, bK, kbuf, trigc, trig, cap, 1);
    if (cap > 0)
        fix_kernel<<<dim3(128), b256, 0, stream>>>(x, WQ, WK, bQ, bK, qbuf, kbuf, trigc, trig, cap);

    score_kernel<<<dim3(BATCH * NHEADS * 4), b256, 0, stream>>>(qbuf, kbuf, Wd, bd, out);
    fires_kernel<<<dim3(BATCH * SEQ * 4), b256, 0, stream>>>(qbuf, kbuf, out);
}

// Round 4
// 333.763 us; speedup vs baseline: 1.5372x; 1.1789x over previous
//
#include <hip/hip_runtime.h>
#include <hip/hip_bf16.h>

#define D_MODEL 768
#define D_HIDDEN 2048
#define NHEADS 12
#define BATCH 4
#define SEQ 128
#define MROWS (BATCH*SEQ)                      // 512
#define SCORE_ELEMS (BATCH*NHEADS*SEQ*SEQ)     // 786432
#define REG_OFF SCORE_ELEMS
#define FIRES_OFF (SCORE_ELEMS + 1)
#define TRIGMAX 8192

typedef __attribute__((ext_vector_type(8))) short bf16x8;
typedef __attribute__((ext_vector_type(4))) float f32x4;

static __device__ __forceinline__ unsigned short f2bf(float f) {
    union { float f; unsigned u; } v; v.f = f;
    unsigned u = v.u;
    return (unsigned short)((u + 0x7FFFu + ((u >> 16) & 1u)) >> 16);  // RNE
}

// ---------------------------------------------------------------------------
// Kernel 0: zero the trigger counter and the reg_loss accumulator slot.
// ---------------------------------------------------------------------------
__global__ void init_kernel(unsigned* __restrict__ trigc, float* __restrict__ reg, int cap) {
    if (threadIdx.x == 0) {
        if (cap > 0) *trigc = 0u;
        *reg = 0.f;
    }
}

// ---------------------------------------------------------------------------
// Kernel 1: fused encoder GEMM  out = relu(x @ W + b) for Q (z=0) and K (z=1).
// M=512, N=2048, K=768. BM=64, BN=128, BK=16, fp32 accum. Grid (16,8,2)=256.
// Near-zero preacts (|pre| < 3e-4) go to a trigger list; fix_kernel recomputes
// them in fp64 so fires signs match the true value.
// ---------------------------------------------------------------------------
__global__ __launch_bounds__(256) void enc_kernel(
    const float* __restrict__ x,
    const float* __restrict__ WQ, const float* __restrict__ WK,
    const float* __restrict__ bQ, const float* __restrict__ bK,
    float* __restrict__ qbuf, float* __restrict__ kbuf,
    unsigned* __restrict__ trigc, unsigned* __restrict__ trig, int cap)
{
    __shared__ float xs[64][16];
    __shared__ float wt[16][128];
    const int bufid = blockIdx.z;
    const float* W    = bufid ? WK : WQ;
    const float* bias = bufid ? bK : bQ;
    float* outbuf     = bufid ? kbuf : qbuf;

    const int t  = threadIdx.x;
    const int m0 = blockIdx.y * 64;
    const int n0 = blockIdx.x * 128;
    const int rg = t >> 5;
    const int cg = t & 31;

    float acc[8][4];
    #pragma unroll
    for (int i = 0; i < 8; ++i)
        #pragma unroll
        for (int c = 0; c < 4; ++c) acc[i][c] = 0.f;

    for (int kk = 0; kk < D_MODEL; kk += 16) {
        #pragma unroll
        for (int u = 0; u < 4; ++u) {
            int idx = t + 256 * u; int r = idx >> 4, j = idx & 15;
            xs[r][j] = x[(size_t)(m0 + r) * D_MODEL + kk + j];
        }
        #pragma unroll
        for (int u = 0; u < 8; ++u) {
            int idx = t + 256 * u; int r = idx >> 7, c = idx & 127;
            wt[r][c] = W[(size_t)(kk + r) * D_HIDDEN + n0 + c];
        }
        __syncthreads();
        #pragma unroll
        for (int j = 0; j < 16; ++j) {
            float a[8];
            #pragma unroll
            for (int i = 0; i < 8; ++i) a[i] = xs[rg * 8 + i][j];
            const float4 wv = *reinterpret_cast<const float4*>(&wt[j][cg * 4]);
            const float wr[4] = {wv.x, wv.y, wv.z, wv.w};
            #pragma unroll
            for (int i = 0; i < 8; ++i)
                #pragma unroll
                for (int c = 0; c < 4; ++c) acc[i][c] = fmaf(a[i], wr[c], acc[i][c]);
        }
        __syncthreads();
    }

    #pragma unroll
    for (int i = 0; i < 8; ++i) {
        const int m = m0 + rg * 8 + i;
        #pragma unroll
        for (int c = 0; c < 4; ++c) {
            const int h = n0 + cg * 4 + c;
            float pre = acc[i][c] + bias[h];
            if (fabsf(pre) < 3e-4f) {
                if (cap > 0) {
                    unsigned idx = atomicAdd(trigc, 1u);
                    if ((int)idx < cap)
                        trig[idx] = ((unsigned)bufid << 20) | ((unsigned)m << 11) | (unsigned)h;
                } else {
                    const float* xr = x + (size_t)m * D_MODEL;
                    const float* wc = W + h;
                    double s = (double)bias[h];
                    for (int dd = 0; dd < D_MODEL; ++dd)
                        s += (double)xr[dd] * (double)wc[(size_t)dd * D_HIDDEN];
                    pre = (float)s;
                }
            }
            outbuf[(size_t)m * D_HIDDEN + h] = fmaxf(pre, 0.f);
        }
    }
}

// ---------------------------------------------------------------------------
// Kernel 1b: fp64 fix for near-zero preacts. One block per trigger (strided).
// ---------------------------------------------------------------------------
__global__ __launch_bounds__(256) void fix_kernel(
    const float* __restrict__ x,
    const float* __restrict__ WQ, const float* __restrict__ WK,
    const float* __restrict__ bQ, const float* __restrict__ bK,
    float* __restrict__ qbuf, float* __restrict__ kbuf,
    const unsigned* __restrict__ trigc, const unsigned* __restrict__ trig,
    int cap)
{
    __shared__ double red[4];
    const unsigned n = min(*trigc, (unsigned)cap);
    for (unsigned i = blockIdx.x; i < n; i += gridDim.x) {
        const unsigned e = trig[i];
        const int h = e & 2047, m = (e >> 11) & 511, bid = (int)(e >> 20);
        const float* W  = bid ? WK : WQ;
        const float* bb = bid ? bK : bQ;
        float* ob       = bid ? kbuf : qbuf;
        const float* xr = x + (size_t)m * D_MODEL;
        double s = 0.0;
        for (int dd = threadIdx.x; dd < D_MODEL; dd += 256)
            s += (double)xr[dd] * (double)W[(size_t)dd * D_HIDDEN + h];
        #pragma unroll
        for (int off = 32; off > 0; off >>= 1) s += __shfl_down(s, off);
        if ((threadIdx.x & 63) == 0) red[threadIdx.x >> 6] = s;
        __syncthreads();
        if (threadIdx.x == 0) {
            double tot = red[0] + red[1] + red[2] + red[3] + (double)bb[h];
            ob[(size_t)m * D_HIDDEN + h] = fmaxf((float)tot, 0.f);
        }
        __syncthreads();
    }
}

// ---------------------------------------------------------------------------
// Kernel 2: fires + reg_loss streaming pass (store-BW bound, ~512 MiB writes)
// PLAIN cached float4 stores (NT bypassed L2 -> 16B HBM granules -> ~1/4 BW).
// Fires row r starts at out index 786433 + r*2048 (== 1 mod 4): h in [3,2046]
// are 511 aligned float4 stores; h in {0,1,2,2047} scalar edge stores.
// grid = 4b * 128q * 4kc blocks; block handles (b,q, 32 k-rows).
// ---------------------------------------------------------------------------
__global__ __launch_bounds__(256) void fires_kernel(
    const float* __restrict__ qbuf, const float* __restrict__ kbuf,
    float* __restrict__ out)
{
    const int t  = threadIdx.x;
    const int bi = blockIdx.x;
    const int kc = bi & 3;
    const int q  = (bi >> 2) & (SEQ - 1);
    const int b  = bi >> 9;

    const float* qrow = qbuf + (size_t)(b * SEQ + q) * D_HIDDEN;

    const int h1 = 3 + 4 * t;          // vector 1: h = 3..1026
    const int h2 = h1 + 1024;          // vector 2: h = 1027..2046 (t<255)
    const bool has2 = (t < 255);

    float qv1[4], qv2[4];
    #pragma unroll
    for (int e = 0; e < 4; ++e) qv1[e] = qrow[h1 + e];
    #pragma unroll
    for (int e = 0; e < 4; ++e) qv2[e] = has2 ? qrow[h2 + e] : 0.f;
    const int he = (t < 3) ? t : 2047;
    const float qve = (t < 4) ? qrow[he] : 0.f;

    float racc = 0.f;
    const size_t rowbase = (size_t)(b * SEQ + q) * SEQ + (size_t)kc * 32;
    const float* kbase = kbuf + (size_t)(b * SEQ + kc * 32) * D_HIDDEN;

    for (int k0 = 0; k0 < 32; ++k0) {
        const float* kr = kbase + (size_t)k0 * D_HIDDEN;
        float* orow = out + FIRES_OFF + (rowbase + k0) * D_HIDDEN;

        f32x4 f1;
        {
            float p0 = qv1[0] * kr[h1 + 0];
            float p1 = qv1[1] * kr[h1 + 1];
            float p2 = qv1[2] * kr[h1 + 2];
            float p3 = qv1[3] * kr[h1 + 3];
            f1.x = (p0 > 0.f) ? 1.f : 0.f;
            f1.y = (p1 > 0.f) ? 1.f : 0.f;
            f1.z = (p2 > 0.f) ? 1.f : 0.f;
            f1.w = (p3 > 0.f) ? 1.f : 0.f;
            racc += sqrtf(p0 + 1e-6f) + sqrtf(p1 + 1e-6f)
                  + sqrtf(p2 + 1e-6f) + sqrtf(p3 + 1e-6f);
        }
        *reinterpret_cast<f32x4*>(orow + h1) = f1;

        if (has2) {
            f32x4 f2;
            float p0 = qv2[0] * kr[h2 + 0];
            float p1 = qv2[1] * kr[h2 + 1];
            float p2 = qv2[2] * kr[h2 + 2];
            float p3 = qv2[3] * kr[h2 + 3];
            f2.x = (p0 > 0.f) ? 1.f : 0.f;
            f2.y = (p1 > 0.f) ? 1.f : 0.f;
            f2.z = (p2 > 0.f) ? 1.f : 0.f;
            f2.w = (p3 > 0.f) ? 1.f : 0.f;
            racc += sqrtf(p0 + 1e-6f) + sqrtf(p1 + 1e-6f)
                  + sqrtf(p2 + 1e-6f) + sqrtf(p3 + 1e-6f);
            *reinterpret_cast<f32x4*>(orow + h2) = f2;
        }

        if (t < 4) {
            const float pe = qve * kr[he];
            orow[he] = (pe > 0.f) ? 1.f : 0.f;
            racc += sqrtf(pe + 1e-6f);
        }
    }

    #pragma unroll
    for (int off = 32; off > 0; off >>= 1) racc += __shfl_down(racc, off);
    __shared__ float rs[4];
    if ((t & 63) == 0) rs[t >> 6] = racc;
    __syncthreads();
    if (t == 0) atomicAdd(out + REG_OFF, (rs[0] + rs[1] + rs[2] + rs[3]) * 1e-3f);
}

// ---------------------------------------------------------------------------
// Kernel 3: score via bf16 MFMA. For each (b,n): C[q,k] = (q .* Wdec[:,n]) @ K^T
// ---------------------------------------------------------------------------
__global__ __launch_bounds__(256) void score_kernel(
    const float* __restrict__ qbuf, const float* __restrict__ kbuf,
    const float* __restrict__ Wdec, const float* __restrict__ bdec,
    float* __restrict__ out)
{
    __shared__ float wcol[D_HIDDEN];
    const int t   = threadIdx.x;
    const int bi  = blockIdx.x;
    const int sub = bi & 3;
    const int pr  = bi >> 2;
    const int n   = pr % NHEADS;
    const int b   = pr / NHEADS;

    for (int idx = t; idx < D_HIDDEN; idx += 256)
        wcol[idx] = Wdec[(size_t)idx * NHEADS + n];
    __syncthreads();

    const int q0   = (sub >> 1) * 64;
    const int k0   = (sub & 1) * 64;
    const int w    = t >> 6;
    const int lane = t & 63;
    const int lrow = lane & 15;
    const int koff = (lane >> 4) * 8;
    const int qw   = q0 + (w >> 1) * 32;
    const int kw   = k0 + (w & 1) * 32;

    f32x4 acc[2][2];
    #pragma unroll
    for (int i = 0; i < 2; ++i)
        #pragma unroll
        for (int j = 0; j < 2; ++j) { f32x4 z = {0.f, 0.f, 0.f, 0.f}; acc[i][j] = z; }

    const float* qb = qbuf + (size_t)b * SEQ * D_HIDDEN;
    const float* kb = kbuf + (size_t)b * SEQ * D_HIDDEN;

    for (int kk = 0; kk < D_HIDDEN; kk += 32) {
        const int h0 = kk + koff;
        float wv[8];
        #pragma unroll
        for (int i = 0; i < 8; ++i) wv[i] = wcol[h0 + i];

        bf16x8 afrag[2], bfrag[2];
        #pragma unroll
        for (int fi = 0; fi < 2; ++fi) {
            const float* qp = qb + (size_t)(qw + fi * 16 + lrow) * D_HIDDEN + h0;
            const float4 q1 = *reinterpret_cast<const float4*>(qp);
            const float4 q2 = *reinterpret_cast<const float4*>(qp + 4);
            const float qf[8] = {q1.x, q1.y, q1.z, q1.w, q2.x, q2.y, q2.z, q2.w};
            #pragma unroll
            for (int i = 0; i < 8; ++i) afrag[fi][i] = (short)f2bf(qf[i] * wv[i]);
        }
        #pragma unroll
        for (int fj = 0; fj < 2; ++fj) {
            const float* kp = kb + (size_t)(kw + fj * 16 + lrow) * D_HIDDEN + h0;
            const float4 k1 = *reinterpret_cast<const float4*>(kp);
            const float4 k2 = *reinterpret_cast<const float4*>(kp + 4);
            const float kf[8] = {k1.x, k1.y, k1.z, k1.w, k2.x, k2.y, k2.z, k2.w};
            #pragma unroll
            for (int i = 0; i < 8; ++i) bfrag[fj][i] = (short)f2bf(kf[i]);
        }
        #pragma unroll
        for (int fi = 0; fi < 2; ++fi)
            #pragma unroll
            for (int fj = 0; fj < 2; ++fj)
                acc[fi][fj] = __builtin_amdgcn_mfma_f32_16x16x32_bf16(
                    afrag[fi], bfrag[fj], acc[fi][fj], 0, 0, 0);
    }

    const float bd   = bdec[n];
    const int   outb = (b * NHEADS + n) * SEQ * SEQ;
    #pragma unroll
    for (int fi = 0; fi < 2; ++fi)
        #pragma unroll
        for (int fj = 0; fj < 2; ++fj)
            #pragma unroll
            for (int j = 0; j < 4; ++j) {
                const int row = qw + fi * 16 + (lane >> 4) * 4 + j;
                const int col = kw + fj * 16 + (lane & 15);
                out[outb + row * SEQ + col] = acc[fi][fj][j] * 0.125f + bd;
            }
}

// ---------------------------------------------------------------------------
extern "C" void kernel_launch(void* const* d_in, const int* in_sizes, int n_in,
                              void* d_out, int out_size, void* d_ws, size_t ws_size,
                              hipStream_t stream) {
    const float* x  = (const float*)d_in[0];
    const float* WQ = (const float*)d_in[1];
    const float* WK = (const float*)d_in[2];
    const float* bQ = (const float*)d_in[3];
    const float* bK = (const float*)d_in[4];
    const float* Wd = (const float*)d_in[5];
    const float* bd = (const float*)d_in[6];
    float* out  = (float*)d_out;
    float* qbuf = (float*)d_ws;                                // 4 MB
    float* kbuf = qbuf + (size_t)MROWS * D_HIDDEN;             // 4 MB
    unsigned* trigc = (unsigned*)(kbuf + (size_t)MROWS * D_HIDDEN);
    unsigned* trig  = trigc + 1;
    const size_t need = (size_t)8 * 1024 * 1024 + 4 + (size_t)TRIGMAX * 4;
    const int cap = (ws_size >= need) ? TRIGMAX : 0;

    dim3 b256(256);

    init_kernel<<<dim3(1), dim3(64), 0, stream>>>(trigc, out + REG_OFF, cap);

    enc_kernel<<<dim3(D_HIDDEN / 128, MROWS / 64, 2), b256, 0, stream>>>(
        x, WQ, WK, bQ, bK, qbuf, kbuf, trigc, trig, cap);
    if (cap > 0)
        fix_kernel<<<dim3(128), b256, 0, stream>>>(x, WQ, WK, bQ, bK, qbuf, kbuf, trigc, trig, cap);

    score_kernel<<<dim3(BATCH * NHEADS * 4), b256, 0, stream>>>(qbuf, kbuf, Wd, bd, out);
    fires_kernel<<<dim3(BATCH * SEQ * 4), b256, 0, stream>>>(qbuf, kbuf, out);
}

// Round 5
// 292.127 us; speedup vs baseline: 1.7563x; 1.1425x over previous
//
#include <hip/hip_runtime.h>
#include <hip/hip_bf16.h>

#define D_MODEL 768
#define D_HIDDEN 2048
#define NHEADS 12
#define BATCH 4
#define SEQ 128
#define MROWS (BATCH*SEQ)                      // 512
#define SCORE_ELEMS (BATCH*NHEADS*SEQ*SEQ)     // 786432
#define REG_OFF SCORE_ELEMS
#define FIRES_OFF (SCORE_ELEMS + 1)
#define TRIGMAX 8192
#define NFIRES_BLOCKS 512

typedef __attribute__((ext_vector_type(8))) short bf16x8;
typedef __attribute__((ext_vector_type(4))) float f32x4;

static __device__ __forceinline__ unsigned short f2bf(float f) {
    union { float f; unsigned u; } v; v.f = f;
    unsigned u = v.u;
    return (unsigned short)((u + 0x7FFFu + ((u >> 16) & 1u)) >> 16);  // RNE
}

// ---------------------------------------------------------------------------
// Kernel 0: zero the trigger counter.
// ---------------------------------------------------------------------------
__global__ void init_kernel(unsigned* __restrict__ trigc) {
    if (threadIdx.x == 0) *trigc = 0u;
}

// ---------------------------------------------------------------------------
// Kernel 1: fused encoder GEMM  out = relu(x @ W + b) for Q (z=0) and K (z=1).
// M=512, N=2048, K=768. BM=64, BN=128, BK=16, fp32 accum. Grid (16,8,2)=256.
// Near-zero preacts (|pre| < 3e-4) go to a trigger list; fix_kernel recomputes
// them in fp64 so fires signs match the true value.
// ---------------------------------------------------------------------------
__global__ __launch_bounds__(256) void enc_kernel(
    const float* __restrict__ x,
    const float* __restrict__ WQ, const float* __restrict__ WK,
    const float* __restrict__ bQ, const float* __restrict__ bK,
    float* __restrict__ qbuf, float* __restrict__ kbuf,
    unsigned* __restrict__ trigc, unsigned* __restrict__ trig, int cap)
{
    __shared__ float xs[64][16];
    __shared__ float wt[16][128];
    const int bufid = blockIdx.z;
    const float* W    = bufid ? WK : WQ;
    const float* bias = bufid ? bK : bQ;
    float* outbuf     = bufid ? kbuf : qbuf;

    const int t  = threadIdx.x;
    const int m0 = blockIdx.y * 64;
    const int n0 = blockIdx.x * 128;
    const int rg = t >> 5;
    const int cg = t & 31;

    float acc[8][4];
    #pragma unroll
    for (int i = 0; i < 8; ++i)
        #pragma unroll
        for (int c = 0; c < 4; ++c) acc[i][c] = 0.f;

    for (int kk = 0; kk < D_MODEL; kk += 16) {
        #pragma unroll
        for (int u = 0; u < 4; ++u) {
            int idx = t + 256 * u; int r = idx >> 4, j = idx & 15;
            xs[r][j] = x[(size_t)(m0 + r) * D_MODEL + kk + j];
        }
        #pragma unroll
        for (int u = 0; u < 8; ++u) {
            int idx = t + 256 * u; int r = idx >> 7, c = idx & 127;
            wt[r][c] = W[(size_t)(kk + r) * D_HIDDEN + n0 + c];
        }
        __syncthreads();
        #pragma unroll
        for (int j = 0; j < 16; ++j) {
            float a[8];
            #pragma unroll
            for (int i = 0; i < 8; ++i) a[i] = xs[rg * 8 + i][j];
            const float4 wv = *reinterpret_cast<const float4*>(&wt[j][cg * 4]);
            const float wr[4] = {wv.x, wv.y, wv.z, wv.w};
            #pragma unroll
            for (int i = 0; i < 8; ++i)
                #pragma unroll
                for (int c = 0; c < 4; ++c) acc[i][c] = fmaf(a[i], wr[c], acc[i][c]);
        }
        __syncthreads();
    }

    #pragma unroll
    for (int i = 0; i < 8; ++i) {
        const int m = m0 + rg * 8 + i;
        #pragma unroll
        for (int c = 0; c < 4; ++c) {
            const int h = n0 + cg * 4 + c;
            float pre = acc[i][c] + bias[h];
            if (fabsf(pre) < 3e-4f) {
                if (cap > 0) {
                    unsigned idx = atomicAdd(trigc, 1u);
                    if ((int)idx < cap)
                        trig[idx] = ((unsigned)bufid << 20) | ((unsigned)m << 11) | (unsigned)h;
                } else {
                    const float* xr = x + (size_t)m * D_MODEL;
                    const float* wc = W + h;
                    double s = (double)bias[h];
                    for (int dd = 0; dd < D_MODEL; ++dd)
                        s += (double)xr[dd] * (double)wc[(size_t)dd * D_HIDDEN];
                    pre = (float)s;
                }
            }
            outbuf[(size_t)m * D_HIDDEN + h] = fmaxf(pre, 0.f);
        }
    }
}

// ---------------------------------------------------------------------------
// Kernel 1b: fp64 fix for near-zero preacts. One block per trigger (strided).
// ---------------------------------------------------------------------------
__global__ __launch_bounds__(256) void fix_kernel(
    const float* __restrict__ x,
    const float* __restrict__ WQ, const float* __restrict__ WK,
    const float* __restrict__ bQ, const float* __restrict__ bK,
    float* __restrict__ qbuf, float* __restrict__ kbuf,
    const unsigned* __restrict__ trigc, const unsigned* __restrict__ trig,
    int cap)
{
    __shared__ double red[4];
    const unsigned n = min(*trigc, (unsigned)cap);
    for (unsigned i = blockIdx.x; i < n; i += gridDim.x) {
        const unsigned e = trig[i];
        const int h = e & 2047, m = (e >> 11) & 511, bid = (int)(e >> 20);
        const float* W  = bid ? WK : WQ;
        const float* bb = bid ? bK : bQ;
        float* ob       = bid ? kbuf : qbuf;
        const float* xr = x + (size_t)m * D_MODEL;
        double s = 0.0;
        for (int dd = threadIdx.x; dd < D_MODEL; dd += 256)
            s += (double)xr[dd] * (double)W[(size_t)dd * D_HIDDEN + h];
        #pragma unroll
        for (int off = 32; off > 0; off >>= 1) s += __shfl_down(s, off);
        if ((threadIdx.x & 63) == 0) red[threadIdx.x >> 6] = s;
        __syncthreads();
        if (threadIdx.x == 0) {
            double tot = red[0] + red[1] + red[2] + red[3] + (double)bb[h];
            ob[(size_t)m * D_HIDDEN + h] = fmaxf((float)tot, 0.f);
        }
        __syncthreads();
    }
}

// ---------------------------------------------------------------------------
// Kernel 2: fires + reg partials. q x k tiled: block = 4 q-rows x 32 k-rows.
// q held in registers (reused 32x); each k-row loaded once (reused 4x).
// Read traffic 540MB -> ~144MB; each k-load feeds 8 independent f32x4 stores.
// Fires row base == 1 mod 4: h in [3,2046] via aligned f32x4; edges scalar.
// grid = 4b * 32qc * 4kc = 512 blocks. Per-block reg partial -> ws (determin.).
// ---------------------------------------------------------------------------
__global__ __launch_bounds__(256) void fires_kernel(
    const float* __restrict__ qbuf, const float* __restrict__ kbuf,
    float* __restrict__ out, float* __restrict__ partial)
{
    const int t  = threadIdx.x;
    const int bi = blockIdx.x;
    const int kc = bi & 3;
    const int qc = (bi >> 2) & 31;
    const int b  = bi >> 7;

    const int h1 = 3 + 4 * t;          // h = 3..1026
    const int h2 = h1 + 1024;          // h = 1027..2046 (t<255)
    const bool has2 = (t < 255);

    const int qrow0 = b * SEQ + qc * 4;
    float qv1[4][4], qv2[4][4];
    #pragma unroll
    for (int r = 0; r < 4; ++r) {
        const float* qr_ = qbuf + (size_t)(qrow0 + r) * D_HIDDEN;
        #pragma unroll
        for (int e = 0; e < 4; ++e) qv1[r][e] = qr_[h1 + e];
        #pragma unroll
        for (int e = 0; e < 4; ++e) qv2[r][e] = has2 ? qr_[h2 + e] : 0.f;
    }
    // edge lanes t<16: row er=t>>2, elem (t&3)<3 ? t&3 : 2047
    const int er = t >> 2;
    const int he = ((t & 3) < 3) ? (t & 3) : 2047;
    const float qve = (t < 16) ? qbuf[(size_t)(qrow0 + er) * D_HIDDEN + he] : 0.f;

    float racc[4] = {0.f, 0.f, 0.f, 0.f};
    float redge = 0.f;

    const float* kbase = kbuf + (size_t)(b * SEQ + kc * 32) * D_HIDDEN;

    for (int k0 = 0; k0 < 32; ++k0) {
        const float* kr = kbase + (size_t)k0 * D_HIDDEN;
        float kv1[4], kv2[4];
        #pragma unroll
        for (int e = 0; e < 4; ++e) kv1[e] = kr[h1 + e];
        #pragma unroll
        for (int e = 0; e < 4; ++e) kv2[e] = has2 ? kr[h2 + e] : 0.f;
        const float kve = (t < 16) ? kr[he] : 0.f;
        const int kcol = kc * 32 + k0;

        #pragma unroll
        for (int r = 0; r < 4; ++r) {
            float* orow = out + FIRES_OFF +
                ((size_t)(qrow0 + r) * SEQ + (size_t)kcol) * D_HIDDEN;
            const float p0 = qv1[r][0] * kv1[0];
            const float p1 = qv1[r][1] * kv1[1];
            const float p2 = qv1[r][2] * kv1[2];
            const float p3 = qv1[r][3] * kv1[3];
            f32x4 f1;
            f1.x = (p0 > 0.f) ? 1.f : 0.f;
            f1.y = (p1 > 0.f) ? 1.f : 0.f;
            f1.z = (p2 > 0.f) ? 1.f : 0.f;
            f1.w = (p3 > 0.f) ? 1.f : 0.f;
            *reinterpret_cast<f32x4*>(orow + h1) = f1;
            float s = (sqrtf(p0 + 1e-6f) + sqrtf(p1 + 1e-6f))
                    + (sqrtf(p2 + 1e-6f) + sqrtf(p3 + 1e-6f));
            if (has2) {
                const float p4 = qv2[r][0] * kv2[0];
                const float p5 = qv2[r][1] * kv2[1];
                const float p6 = qv2[r][2] * kv2[2];
                const float p7 = qv2[r][3] * kv2[3];
                f32x4 f2;
                f2.x = (p4 > 0.f) ? 1.f : 0.f;
                f2.y = (p5 > 0.f) ? 1.f : 0.f;
                f2.z = (p6 > 0.f) ? 1.f : 0.f;
                f2.w = (p7 > 0.f) ? 1.f : 0.f;
                *reinterpret_cast<f32x4*>(orow + h2) = f2;
                s += (sqrtf(p4 + 1e-6f) + sqrtf(p5 + 1e-6f))
                   + (sqrtf(p6 + 1e-6f) + sqrtf(p7 + 1e-6f));
            }
            racc[r] += s;
        }

        if (t < 16) {
            float* orow = out + FIRES_OFF +
                ((size_t)(qrow0 + er) * SEQ + (size_t)kcol) * D_HIDDEN;
            const float pe = qve * kve;
            orow[he] = (pe > 0.f) ? 1.f : 0.f;
            redge += sqrtf(pe + 1e-6f);
        }
    }

    float rt = ((racc[0] + racc[1]) + (racc[2] + racc[3])) + redge;
    #pragma unroll
    for (int off = 32; off > 0; off >>= 1) rt += __shfl_down(rt, off);
    __shared__ float rs[4];
    if ((t & 63) == 0) rs[t >> 6] = rt;
    __syncthreads();
    if (t == 0) partial[bi] = (rs[0] + rs[1]) + (rs[2] + rs[3]);
}

// ---------------------------------------------------------------------------
// Kernel 2b: deterministic fixed-order reduction of block partials -> reg_loss.
// ---------------------------------------------------------------------------
__global__ __launch_bounds__(256) void reduce_kernel(
    const float* __restrict__ partial, float* __restrict__ reg)
{
    __shared__ float rs[4];
    const int t = threadIdx.x;
    float s = partial[t] + partial[t + 256];
    #pragma unroll
    for (int off = 32; off > 0; off >>= 1) s += __shfl_down(s, off);
    if ((t & 63) == 0) rs[t >> 6] = s;
    __syncthreads();
    if (t == 0) *reg = ((rs[0] + rs[1]) + (rs[2] + rs[3])) * 1e-3f;
}

// ---------------------------------------------------------------------------
// Kernel 3: score via bf16 MFMA. For each (b,n): C[q,k] = (q .* Wdec[:,n]) @ K^T
// ---------------------------------------------------------------------------
__global__ __launch_bounds__(256) void score_kernel(
    const float* __restrict__ qbuf, const float* __restrict__ kbuf,
    const float* __restrict__ Wdec, const float* __restrict__ bdec,
    float* __restrict__ out)
{
    __shared__ float wcol[D_HIDDEN];
    const int t   = threadIdx.x;
    const int bi  = blockIdx.x;
    const int sub = bi & 3;
    const int pr  = bi >> 2;
    const int n   = pr % NHEADS;
    const int b   = pr / NHEADS;

    for (int idx = t; idx < D_HIDDEN; idx += 256)
        wcol[idx] = Wdec[(size_t)idx * NHEADS + n];
    __syncthreads();

    const int q0   = (sub >> 1) * 64;
    const int k0   = (sub & 1) * 64;
    const int w    = t >> 6;
    const int lane = t & 63;
    const int lrow = lane & 15;
    const int koff = (lane >> 4) * 8;
    const int qw   = q0 + (w >> 1) * 32;
    const int kw   = k0 + (w & 1) * 32;

    f32x4 acc[2][2];
    #pragma unroll
    for (int i = 0; i < 2; ++i)
        #pragma unroll
        for (int j = 0; j < 2; ++j) { f32x4 z = {0.f, 0.f, 0.f, 0.f}; acc[i][j] = z; }

    const float* qb = qbuf + (size_t)b * SEQ * D_HIDDEN;
    const float* kb = kbuf + (size_t)b * SEQ * D_HIDDEN;

    for (int kk = 0; kk < D_HIDDEN; kk += 32) {
        const int h0 = kk + koff;
        float wv[8];
        #pragma unroll
        for (int i = 0; i < 8; ++i) wv[i] = wcol[h0 + i];

        bf16x8 afrag[2], bfrag[2];
        #pragma unroll
        for (int fi = 0; fi < 2; ++fi) {
            const float* qp = qb + (size_t)(qw + fi * 16 + lrow) * D_HIDDEN + h0;
            const float4 q1 = *reinterpret_cast<const float4*>(qp);
            const float4 q2 = *reinterpret_cast<const float4*>(qp + 4);
            const float qf[8] = {q1.x, q1.y, q1.z, q1.w, q2.x, q2.y, q2.z, q2.w};
            #pragma unroll
            for (int i = 0; i < 8; ++i) afrag[fi][i] = (short)f2bf(qf[i] * wv[i]);
        }
        #pragma unroll
        for (int fj = 0; fj < 2; ++fj) {
            const float* kp = kb + (size_t)(kw + fj * 16 + lrow) * D_HIDDEN + h0;
            const float4 k1 = *reinterpret_cast<const float4*>(kp);
            const float4 k2 = *reinterpret_cast<const float4*>(kp + 4);
            const float kf[8] = {k1.x, k1.y, k1.z, k1.w, k2.x, k2.y, k2.z, k2.w};
            #pragma unroll
            for (int i = 0; i < 8; ++i) bfrag[fj][i] = (short)f2bf(kf[i]);
        }
        #pragma unroll
        for (int fi = 0; fi < 2; ++fi)
            #pragma unroll
            for (int fj = 0; fj < 2; ++fj)
                acc[fi][fj] = __builtin_amdgcn_mfma_f32_16x16x32_bf16(
                    afrag[fi], bfrag[fj], acc[fi][fj], 0, 0, 0);
    }

    const float bd   = bdec[n];
    const int   outb = (b * NHEADS + n) * SEQ * SEQ;
    #pragma unroll
    for (int fi = 0; fi < 2; ++fi)
        #pragma unroll
        for (int fj = 0; fj < 2; ++fj)
            #pragma unroll
            for (int j = 0; j < 4; ++j) {
                const int row = qw + fi * 16 + (lane >> 4) * 4 + j;
                const int col = kw + fj * 16 + (lane & 15);
                out[outb + row * SEQ + col] = acc[fi][fj][j] * 0.125f + bd;
            }
}

// ---------------------------------------------------------------------------
extern "C" void kernel_launch(void* const* d_in, const int* in_sizes, int n_in,
                              void* d_out, int out_size, void* d_ws, size_t ws_size,
                              hipStream_t stream) {
    const float* x  = (const float*)d_in[0];
    const float* WQ = (const float*)d_in[1];
    const float* WK = (const float*)d_in[2];
    const float* bQ = (const float*)d_in[3];
    const float* bK = (const float*)d_in[4];
    const float* Wd = (const float*)d_in[5];
    const float* bd = (const float*)d_in[6];
    float* out  = (float*)d_out;
    float* qbuf = (float*)d_ws;                                // 4 MB
    float* kbuf = qbuf + (size_t)MROWS * D_HIDDEN;             // 4 MB
    float* partial = kbuf + (size_t)MROWS * D_HIDDEN;          // 512 floats
    unsigned* trigc = (unsigned*)(partial + NFIRES_BLOCKS);
    unsigned* trig  = trigc + 1;
    const size_t need = (size_t)8 * 1024 * 1024 + NFIRES_BLOCKS * 4 + 4 + (size_t)TRIGMAX * 4;
    const int cap = (ws_size >= need) ? TRIGMAX : 0;

    dim3 b256(256);

    if (cap > 0) init_kernel<<<dim3(1), dim3(64), 0, stream>>>(trigc);

    enc_kernel<<<dim3(D_HIDDEN / 128, MROWS / 64, 2), b256, 0, stream>>>(
        x, WQ, WK, bQ, bK, qbuf, kbuf, trigc, trig, cap);
    if (cap > 0)
        fix_kernel<<<dim3(128), b256, 0, stream>>>(x, WQ, WK, bQ, bK, qbuf, kbuf, trigc, trig, cap);

    score_kernel<<<dim3(BATCH * NHEADS * 4), b256, 0, stream>>>(qbuf, kbuf, Wd, bd, out);
    fires_kernel<<<dim3(NFIRES_BLOCKS), b256, 0, stream>>>(qbuf, kbuf, out, partial);
    reduce_kernel<<<dim3(1), b256, 0, stream>>>(partial, out + REG_OFF);
}